// Round 16
// baseline (47.826 us; speedup 1.0000x reference)
//
#include <hip/hip_runtime.h>
#include <hip/hip_fp16.h>

#define BB   128
#define TT   512
#define FF   40
#define WW   10
#define NS   503            // window starts (stride 1): T-W+1
#define NP   780            // F*(F-1)/2 ; 780 = 4*195 exactly
#define SC   64             // steps per block (uniform; last chunk overlaps)
#define NCHUNK 8
#define ROWS (SC + WW - 1)  // 73 staged rows
#define NT   256            // threads per block (4 waves)
#define NQ   195            // threads owning 4 consecutive pairs (4*195 = 780)
#define EPSC 1e-5f
#define C01  0.31622776601683794f   // sqrt(0.1)

// r13 math/structure with ONE delta: thread t (<195) owns pairs 4t..4t+3 and
// stores one aligned float4 per step -> wave emits a dense 1KB store burst
// (vs 256B dword bursts). 780%4==0 so coverage is exact: no masking, no dups.
// Stores stay lane-consecutive in p-space (r5's amplification came from
// scattered (i,j0) strips; this is dense). No min-waves hint (r7/r10 lesson).
__global__ __launch_bounds__(NT) void ts_corr_r16(const float* __restrict__ in,
                                                  float* __restrict__ out) {
    const int blk = blockIdx.x;
    const int b   = blk >> 3;              // / NCHUNK
    const int c   = blk & (NCHUNK - 1);
    const int s0  = (c == NCHUNK - 1) ? (NS - SC) : c * SC;   // 439 tail; overlap rows identical
    const int tid = threadIdx.x;

    __shared__ float   xs[SC + WW][FF];  // 74 rows (73 used + pad) = 11840 B
    __shared__ __half2 st[SC][FF];       // packed (u*sqrt(0.1), m*u) = 10240 B

    // ---- phase 0: stage 73-row slab, float4 (730 quads) ----
    const float4* src4 = (const float4*)(in + ((size_t)b * TT + s0) * FF);
    float4* xs4 = (float4*)&xs[0][0];
    #pragma unroll
    for (int k = 0; k < 3; ++k) {
        const int i = tid + k * NT;
        if (i < ROWS * FF / 4) xs4[i] = src4[i];
    }
    __syncthreads();

    // ---- phase 1: stats for all 64 steps (640 feature-quads), f16-packed ----
    #pragma unroll
    for (int k = 0; k < 3; ++k) {
        const int qd = tid + k * NT;
        if (qd < SC * FF / 4) {
            const int t  = qd / 10;
            const int f0 = (qd - t * 10) * 4;
            float sx0=0,sx1=0,sx2=0,sx3=0, sq0=0,sq1=0,sq2=0,sq3=0;
            #pragma unroll
            for (int w = 0; w < WW; ++w) {
                const float4 x = *(const float4*)&xs[t + w][f0];
                sx0 += x.x; sx1 += x.y; sx2 += x.z; sx3 += x.w;
                sq0 += x.x*x.x; sq1 += x.y*x.y; sq2 += x.z*x.z; sq3 += x.w*x.w;
            }
            const float m0 = sx0*0.1f, m1 = sx1*0.1f, m2 = sx2*0.1f, m3 = sx3*0.1f;
            const float u0 = 1.f/(sqrtf(fmaxf(sq0*0.1f - m0*m0, 0.f)) + EPSC);
            const float u1 = 1.f/(sqrtf(fmaxf(sq1*0.1f - m1*m1, 0.f)) + EPSC);
            const float u2 = 1.f/(sqrtf(fmaxf(sq2*0.1f - m2*m2, 0.f)) + EPSC);
            const float u3 = 1.f/(sqrtf(fmaxf(sq3*0.1f - m3*m3, 0.f)) + EPSC);
            st[t][f0]     = __floats2half2_rn(u0*C01, m0*u0);
            st[t][f0 + 1] = __floats2half2_rn(u1*C01, m1*u1);
            st[t][f0 + 2] = __floats2half2_rn(u2*C01, m2*u2);
            st[t][f0 + 3] = __floats2half2_rn(u3*C01, m3*u3);
        }
    }

    // ---- pair setup: 4 consecutive pairs p = 4*tid..4*tid+3 (clamped for tid>=NQ) ----
    int pi[4], pj[4];
    float sxy[4], ph[4][WW];
    const int pbase = 4 * min(tid, NQ - 1);
    #pragma unroll
    for (int q = 0; q < 4; ++q) {
        const int p = pbase + q;
        int i = (int)((79.0f - sqrtf((float)(6241 - 8 * p))) * 0.5f);
        while (i > 0 && i * (79 - i) / 2 > p) --i;
        while ((i + 1) * (79 - (i + 1)) / 2 <= p) ++i;
        pi[q] = i;
        pj[q] = p - i * (79 - i) / 2 + i + 1;
        float s = 0.f;
        #pragma unroll
        for (int w = 0; w < WW; ++w) {
            const float pr = xs[w][pi[q]] * xs[w][pj[q]];
            ph[q][w] = pr;
            s += pr;
        }
        sxy[q] = s;
    }
    __syncthreads();   // st ready; no barriers after this

    if (tid >= NQ) return;   // waves 0-2 full; wave 3 keeps lanes 0-2

    float* dst0 = out + (size_t)(b * NS + s0) * NP + 4 * tid;

// Two steps (TA, TA+1); U, DO2 literals. Each step stores ONE aligned float4.
#define STEP2(U, TA, DO2) do {                                                  \
    float4 _vA, _vB;                                                            \
    _Pragma("unroll")                                                           \
    for (int q = 0; q < 4; ++q) {                                               \
        const int _ii = pi[q], _jj = pj[q];                                     \
        const float  _xiA = xs[(TA) + WW][_ii], _xiB = xs[(TA) + WW + 1][_ii];  \
        const float  _xjA = xs[(TA) + WW][_jj], _xjB = xs[(TA) + WW + 1][_jj];  \
        const float2 _siA = __half22float2(st[(TA)][_ii]);                      \
        const float2 _siB = __half22float2(st[(TA) + 1][_ii]);                  \
        const float2 _sjA = __half22float2(st[(TA)][_jj]);                      \
        const float2 _sjB = __half22float2(st[(TA) + 1][_jj]);                  \
        (&_vA.x)[q] = sxy[q] * _siA.x * _sjA.x - _siA.y * _sjA.y;               \
        const float _pn = _xiA * _xjA;                                          \
        sxy[q] += _pn - ph[q][U]; ph[q][U] = _pn;                               \
        (&_vB.x)[q] = sxy[q] * _siB.x * _sjB.x - _siB.y * _sjB.y;               \
        if (DO2) {                                                              \
            const float _p2 = _xiB * _xjB;                                      \
            sxy[q] += _p2 - ph[q][(U) + 1]; ph[q][(U) + 1] = _p2;               \
        }                                                                       \
    }                                                                           \
    *(float4*)(dst0 + (size_t)(TA) * NP)     = _vA;                             \
    *(float4*)(dst0 + (size_t)(TA + 1) * NP) = _vB;                             \
} while (0)

    // ---- phase 2: t = 0..59 regular, epilogue t = 60..63 ----
    for (int t0 = 0; t0 < 60; t0 += WW) {
        STEP2(0, t0,     true);
        STEP2(2, t0 + 2, true);
        STEP2(4, t0 + 4, true);
        STEP2(6, t0 + 6, true);
        STEP2(8, t0 + 8, true);
    }
    STEP2(0, 60, true);
    STEP2(2, 62, false);   // B-update reads pad row 73; discarded (DO2=false)
#undef STEP2
}

extern "C" void kernel_launch(void* const* d_in, const int* in_sizes, int n_in,
                              void* d_out, int out_size, void* d_ws, size_t ws_size,
                              hipStream_t stream) {
    const float* in = (const float*)d_in[0];
    float* out = (float*)d_out;
    ts_corr_r16<<<BB * NCHUNK, NT, 0, stream>>>(in, out);
}

// Round 17
// 44.552 us; speedup vs baseline: 1.0735x; 1.0735x over previous
//
#include <hip/hip_runtime.h>
#include <hip/hip_fp16.h>

#define BB   128
#define TT   512
#define FF   40
#define WW   10
#define NS   503            // window starts (stride 1): T-W+1
#define NP   780            // F*(F-1)/2
#define SC   64             // steps per block (uniform; last chunk overlaps)
#define NCHUNK 8
#define ROWS (SC + WW - 1)  // 73 staged rows
#define NT   512            // threads per block (8 waves)
#define EPSC 1e-5f
#define C01  0.31622776601683794f   // sqrt(0.1)

// r13 structure + 1-deep SOFTWARE PIPELINE of the LDS reads: each body issues
// the NEXT step-pair's 8 LDS reads into a dedicated register set (e/o
// alternating, all names static), then computes+stores the CURRENT step-pair
// from registers filled last body. Rationale: we are store-BW-bound; a wave
// issue-stalls on its stores, and reads placed after stores in program order
// can't issue during the stall -> LDS time was ADDING to store time (44 = 29+15).
// Prefetching moves the reads before the stall point.
__global__ __launch_bounds__(NT) void ts_corr_r17(const float* __restrict__ in,
                                                  float* __restrict__ out) {
    const int blk = blockIdx.x;
    const int b   = blk >> 3;              // / NCHUNK
    const int c   = blk & (NCHUNK - 1);
    const int s0  = (c == NCHUNK - 1) ? (NS - SC) : c * SC;   // 439 tail; overlap rows identical
    const int tid = threadIdx.x;

    __shared__ float   xs[SC + WW][FF];  // 74 rows (73 used + pad) = 11840 B
    __shared__ __half2 st[SC][FF];       // packed (u*sqrt(0.1), m*u) = 10240 B

    // ---- phase 0: stage 73-row slab, float4 (730 quads) ----
    const float4* src4 = (const float4*)(in + ((size_t)b * TT + s0) * FF);
    float4* xs4 = (float4*)&xs[0][0];
    {
        xs4[tid] = src4[tid];                       // 0..511
        const int i2 = tid + NT;
        if (i2 < ROWS * FF / 4) xs4[i2] = src4[i2]; // 512..729
    }
    __syncthreads();

    // ---- phase 1: stats for all 64 steps (640 feature-quads), f16-packed ----
    #pragma unroll
    for (int k = 0; k < 2; ++k) {
        const int qd = tid + k * NT;
        if (qd < SC * FF / 4) {
            const int t  = qd / 10;
            const int f0 = (qd - t * 10) * 4;
            float sx0=0,sx1=0,sx2=0,sx3=0, sq0=0,sq1=0,sq2=0,sq3=0;
            #pragma unroll
            for (int w = 0; w < WW; ++w) {
                const float4 x = *(const float4*)&xs[t + w][f0];
                sx0 += x.x; sx1 += x.y; sx2 += x.z; sx3 += x.w;
                sq0 += x.x*x.x; sq1 += x.y*x.y; sq2 += x.z*x.z; sq3 += x.w*x.w;
            }
            const float m0 = sx0*0.1f, m1 = sx1*0.1f, m2 = sx2*0.1f, m3 = sx3*0.1f;
            const float u0 = 1.f/(sqrtf(fmaxf(sq0*0.1f - m0*m0, 0.f)) + EPSC);
            const float u1 = 1.f/(sqrtf(fmaxf(sq1*0.1f - m1*m1, 0.f)) + EPSC);
            const float u2 = 1.f/(sqrtf(fmaxf(sq2*0.1f - m2*m2, 0.f)) + EPSC);
            const float u3 = 1.f/(sqrtf(fmaxf(sq3*0.1f - m3*m3, 0.f)) + EPSC);
            st[t][f0]     = __floats2half2_rn(u0*C01, m0*u0);
            st[t][f0 + 1] = __floats2half2_rn(u1*C01, m1*u1);
            st[t][f0 + 2] = __floats2half2_rn(u2*C01, m2*u2);
            st[t][f0 + 3] = __floats2half2_rn(u3*C01, m3*u3);
        }
    }

    // ---- pair setup + initial window (xs ready since phase-0 barrier) ----
    int pi[2], pj[2];
    float sxy[2], ph[2][WW];
    #pragma unroll
    for (int k = 0; k < 2; ++k) {
        const int p = tid + k * NT;
        const int pp = (p < NP) ? p : 0;
        int i = (int)((79.0f - sqrtf((float)(6241 - 8 * pp))) * 0.5f);
        while (i > 0 && i * (79 - i) / 2 > pp) --i;
        while ((i + 1) * (79 - (i + 1)) / 2 <= pp) ++i;
        pi[k] = i;
        pj[k] = pp - i * (79 - i) / 2 + i + 1;
        float s = 0.f;
        #pragma unroll
        for (int w = 0; w < WW; ++w) {
            const float pr = xs[w][pi[k]] * xs[w][pj[k]];
            ph[k][w] = pr;
            s += pr;
        }
        sxy[k] = s;
    }
    __syncthreads();   // st ready; no barriers after this

    const bool act1 = (tid < NP - NT);   // slot-1 live (tid<268); wave-uniform skip waves 5..7
    float* dst0 = out + (size_t)(b * NS + s0) * NP + tid;

    // prefetch register sets (all names static; no runtime indexing)
#define DECL_SET(P) \
    float   P##xiA0, P##xiB0, P##xjA0, P##xjB0, P##xiA1, P##xiB1, P##xjA1, P##xjB1; \
    __half2 P##siA0, P##siB0, P##sjA0, P##sjB0, P##siA1, P##siB1, P##sjA1, P##sjB1;
    DECL_SET(e)
    DECL_SET(o)

// issue the 8 LDS reads for steps (TA, TA+1) of slot K into set P
#define PREF_SLOT(P, K, TA) do {                                                \
    P##xiA##K = xs[(TA) + WW][pi[K]];   P##xiB##K = xs[(TA) + WW + 1][pi[K]];   \
    P##xjA##K = xs[(TA) + WW][pj[K]];   P##xjB##K = xs[(TA) + WW + 1][pj[K]];   \
    P##siA##K = st[(TA)][pi[K]];        P##siB##K = st[(TA) + 1][pi[K]];        \
    P##sjA##K = st[(TA)][pj[K]];        P##sjB##K = st[(TA) + 1][pj[K]];        \
} while (0)

// compute + store steps (TA, TA+1) of slot K from set P; U, DO2 literals
#define USE_SLOT(P, K, OFF, U, DO2) do {                                        \
    const float2 _siA = __half22float2(P##siA##K);                              \
    const float2 _sjA = __half22float2(P##sjA##K);                              \
    const float2 _siB = __half22float2(P##siB##K);                              \
    const float2 _sjB = __half22float2(P##sjB##K);                              \
    _dA[OFF] = sxy[K] * _siA.x * _sjA.x - _siA.y * _sjA.y;                      \
    const float _pn = P##xiA##K * P##xjA##K;                                    \
    sxy[K] += _pn - ph[K][U]; ph[K][U] = _pn;                                   \
    _dB[OFF] = sxy[K] * _siB.x * _sjB.x - _siB.y * _sjB.y;                      \
    if (DO2) {                                                                  \
        const float _p2 = P##xiB##K * P##xjB##K;                                \
        sxy[K] += _p2 - ph[K][(U) + 1]; ph[K][(U) + 1] = _p2;                   \
    }                                                                           \
} while (0)

// body: prefetch set NXT for TA+2, then compute+store TA/TA+1 from set CUR
#define STEP2P(CUR, NXT, U, TA, DO2, DOPREF) do {                               \
    float* _dA = dst0 + (size_t)(TA) * NP;                                      \
    float* _dB = _dA + NP;                                                      \
    if (DOPREF) PREF_SLOT(NXT, 0, (TA) + 2);                                    \
    USE_SLOT(CUR, 0, 0, U, DO2);                                                \
    if (act1) {                                                                 \
        if (DOPREF) PREF_SLOT(NXT, 1, (TA) + 2);                                \
        USE_SLOT(CUR, 1, NT, U, DO2);                                           \
    }                                                                           \
} while (0)

    // ---- prologue: fill set e for t=0 ----
    PREF_SLOT(e, 0, 0);
    if (act1) PREF_SLOT(e, 1, 0);

    // ---- phase 2: 10 bodies per 20 steps (parity static), 3 groups + epilogue ----
    for (int t0 = 0; t0 < 60; t0 += 20) {
        STEP2P(e, o, 0, t0,      true, true);
        STEP2P(o, e, 2, t0 + 2,  true, true);
        STEP2P(e, o, 4, t0 + 4,  true, true);
        STEP2P(o, e, 6, t0 + 6,  true, true);
        STEP2P(e, o, 8, t0 + 8,  true, true);
        STEP2P(o, e, 0, t0 + 10, true, true);
        STEP2P(e, o, 2, t0 + 12, true, true);
        STEP2P(o, e, 4, t0 + 14, true, true);
        STEP2P(e, o, 6, t0 + 16, true, true);
        STEP2P(o, e, 8, t0 + 18, true, true);
    }
    // t=60: prefetch t=62 (xs row 73 = pad garbage -> only feeds the DO2=false
    // discarded update; st[62],st[63] valid). t=62: no prefetch, DO2=false.
    STEP2P(e, o, 0, 60, true,  true);
    STEP2P(o, e, 2, 62, false, false);
#undef STEP2P
#undef USE_SLOT
#undef PREF_SLOT
#undef DECL_SET
}

extern "C" void kernel_launch(void* const* d_in, const int* in_sizes, int n_in,
                              void* d_out, int out_size, void* d_ws, size_t ws_size,
                              hipStream_t stream) {
    const float* in = (const float*)d_in[0];
    float* out = (float*)d_out;
    ts_corr_r17<<<BB * NCHUNK, NT, 0, stream>>>(in, out);
}